// Round 12
// baseline (445.796 us; speedup 1.0000x reference)
//
#include <hip/hip_runtime.h>

#define NN 20000
#define NE 640000
#define Cc 128
#define C2 256
#define BN_EPS 1e-5f

typedef __attribute__((ext_vector_type(8))) short bf16x8;
typedef __attribute__((ext_vector_type(4))) float f32x4;

// ---- workspace layout (float offsets) ----
#define WS_P     0                      // [NN*Cc]
#define WS_Q     (NN*Cc)                // [NN*Cc]
#define WS_CNTT  (2*NN*Cc)              // [NN] float
#define WS_CNTS  (2*NN*Cc + NN)         // [NN] int
#define WS_STATS (2*NN*Cc + 2*NN)       // [768]: sum1[256], sq1[256], sum2[128], sq2[128]
#define WS_W1PT  (WS_STATS + 768)       // [256*128] transposed folded W1: [c][o]
#define WS_B1P   (WS_W1PT + C2*Cc)      // [128]
#define WS_W2BF  (WS_B1P + Cc)          // ushort[128*128] folded W2 bf16: [o][c]
#define WS_B2P   (WS_W2BF + Cc*Cc)      // [128]
#define WS_PART  (WS_B2P + 128)         // [2500*256] per-block BN2 partials

// z (bf16) for edge e lives in the FIRST 256 B of out-row e's 512 B slot:
// ushort index e*256 + c. Written by k_stats2, read (then overwritten) by
// k_out_mfma's own wave -> no race (reads complete into regs before stores).

// fp32 -> bf16 round-to-nearest-even
static __device__ inline unsigned short f2bf(float f) {
  union { float f; unsigned u; } v; v.f = f;
  unsigned r = v.u + 0x7fffu + ((v.u >> 16) & 1u);
  return (unsigned short)(r >> 16);
}

__global__ void k_zero(float* __restrict__ stats, int* __restrict__ cntS) {
  int i = blockIdx.x * blockDim.x + threadIdx.x;
  if (i < 768) stats[i] = 0.0f;
  if (i < NN) cntS[i] = 0;
}

__global__ void k_cnt(const int* __restrict__ src, int* __restrict__ cntS) {
  int e = blockIdx.x * blockDim.x + threadIdx.x;
  if (e < NE) atomicAdd(&cntS[src[e]], 1);
}

// one block (128 threads) per node: segment sum of x[src] over the node's
// contiguous (tgt sorted) edge range, found by binary search.
__global__ void k_nbr(const float* __restrict__ x, const int* __restrict__ tgt,
                      const int* __restrict__ src, float* __restrict__ nbr,
                      float* __restrict__ cntT) {
  int node = blockIdx.x;
  int a = 0, b = NE;
  while (a < b) { int m = (a + b) >> 1; if (tgt[m] < node) a = m + 1; else b = m; }
  int lo = a;
  b = NE;
  while (a < b) { int m = (a + b) >> 1; if (tgt[m] <= node) a = m + 1; else b = m; }
  int hi = a;
  int c = threadIdx.x;
  float acc = 0.0f;
  for (int e = lo; e < hi; ++e) acc += x[src[e] * Cc + c];
  nbr[node * Cc + c] = acc;
  if (c == 0) cntT[node] = (float)(hi - lo);
}

// BN1 stats: count-weighted sums over nodes.
__global__ void k_stats1(const float* __restrict__ nbr, const float* __restrict__ x,
                         const float* __restrict__ cntT, const int* __restrict__ cntS,
                         float* __restrict__ stats) {
  int c = threadIdx.x;
  float sa = 0.f, qa = 0.f, sb = 0.f, qb = 0.f;
  for (int t = blockIdx.x; t < NN; t += gridDim.x) {
    float ct = cntT[t];
    float cs = (float)cntS[t];
    float v1 = nbr[t * Cc + c];
    float v2 = x[t * Cc + c];
    sa += ct * v1; qa += ct * v1 * v1;
    sb += cs * v2; qb += cs * v2 * v2;
  }
  atomicAdd(&stats[c], sa);
  atomicAdd(&stats[256 + c], qa);
  atomicAdd(&stats[128 + c], sb);
  atomicAdd(&stats[256 + 128 + c], qb);
}

// fold BN1 into W1: W1pT[c][o] = W1[o][c]*a1[c];  b1p[o] = b1[o] + sum_c W1[o][c]*c1[c]
__global__ void k_fold1(const float* __restrict__ W1, const float* __restrict__ b1,
                        const float* __restrict__ g1, const float* __restrict__ be1,
                        const float* __restrict__ stats,
                        float* __restrict__ W1pT, float* __restrict__ b1p) {
  __shared__ float red[C2];
  int o = blockIdx.x, c = threadIdx.x;
  const float inv = 1.0f / (float)NE;
  float mu = stats[c] * inv;
  float var = stats[256 + c] * inv - mu * mu;
  float a = g1[c] * rsqrtf(var + BN_EPS);
  float cc = be1[c] - mu * a;
  float w = W1[o * C2 + c];
  W1pT[c * Cc + o] = w * a;
  red[c] = w * cc;
  __syncthreads();
  for (int s = 128; s > 0; s >>= 1) { if (c < s) red[c] += red[c + s]; __syncthreads(); }
  if (c == 0) b1p[o] = b1[o] + red[0];
}

// P = nbr_sum @ W1a'.T ; Q = x @ W1b'.T   (blockIdx.y selects half)
__global__ __launch_bounds__(256) void k_pq(const float* __restrict__ nbr,
                                            const float* __restrict__ x,
                                            const float* __restrict__ W1pT,
                                            float* __restrict__ P,
                                            float* __restrict__ Q) {
  __shared__ float Ar[32][128];
  const int half = blockIdx.y;
  const float* __restrict__ A = half ? x : nbr;
  float* __restrict__ Out = half ? Q : P;
  const float* __restrict__ Wt = W1pT + (half ? Cc * Cc : 0);  // [128 c][128 o]
  int tid = threadIdx.x;
  int r0 = blockIdx.x * 32;
  for (int i = tid; i < 32 * 128; i += 256) {
    int r = i >> 7, c = i & 127;
    Ar[r][c] = A[(r0 + r) * Cc + c];
  }
  __syncthreads();
  int tx = tid & 31, ty = tid >> 5;
  float acc[4][4] = {};
  #pragma unroll 4
  for (int c = 0; c < 128; ++c) {
    float4 w = *(const float4*)&Wt[c * Cc + tx * 4];
    float a0 = Ar[ty * 4 + 0][c], a1 = Ar[ty * 4 + 1][c];
    float a2 = Ar[ty * 4 + 2][c], a3 = Ar[ty * 4 + 3][c];
    acc[0][0] += a0 * w.x; acc[0][1] += a0 * w.y; acc[0][2] += a0 * w.z; acc[0][3] += a0 * w.w;
    acc[1][0] += a1 * w.x; acc[1][1] += a1 * w.y; acc[1][2] += a1 * w.z; acc[1][3] += a1 * w.w;
    acc[2][0] += a2 * w.x; acc[2][1] += a2 * w.y; acc[2][2] += a2 * w.z; acc[2][3] += a2 * w.w;
    acc[3][0] += a3 * w.x; acc[3][1] += a3 * w.y; acc[3][2] += a3 * w.z; acc[3][3] += a3 * w.w;
  }
  #pragma unroll
  for (int i = 0; i < 4; ++i) {
    int node = r0 + ty * 4 + i;
    float4 v = make_float4(acc[i][0], acc[i][1], acc[i][2], acc[i][3]);
    *(float4*)&Out[node * Cc + tx * 4] = v;
  }
}

// BN2 stats + z materialization, occupancy-fixed: 2500 blocks x 256 threads
// (2 edge-stripes x 128 channels, 128 serial edges each). NO atomics here --
// per-block partials to ws, reduced by k_red.
__global__ __launch_bounds__(256) void k_stats2(const float* __restrict__ P,
                                                const float* __restrict__ Q,
                                                const float* __restrict__ b1p,
                                                const int* __restrict__ tgt,
                                                const int* __restrict__ src,
                                                unsigned short* __restrict__ zout,
                                                float* __restrict__ part) {
  __shared__ float s2[Cc], q2[Cc];
  int c = threadIdx.x & 127;
  int y = threadIdx.x >> 7;
  int e0 = blockIdx.x * 256 + y * 128;
  float b = b1p[c];
  float s = 0.f, q = 0.f;
  for (int e = e0; e < e0 + 128; ++e) {
    int t = tgt[e], sc = src[e];
    float z = fmaxf(P[t * Cc + c] + Q[sc * Cc + c] + b, 0.f);
    zout[(size_t)e * 256 + c] = f2bf(z);
    s += z; q += z * z;
  }
  if (y) { s2[c] = s; q2[c] = q; }
  __syncthreads();
  if (!y) {
    part[(size_t)blockIdx.x * 256 + c] = s + s2[c];
    part[(size_t)blockIdx.x * 256 + 128 + c] = q + q2[c];
  }
}

// reduce 2500 partial rows into stats[512..767]; 25 blocks x 100 rows.
__global__ void k_red(const float* __restrict__ part, float* __restrict__ stats) {
  int tid = threadIdx.x;           // 0..255: <128 -> sum, >=128 -> sumsq
  int r0 = blockIdx.x * 100;
  float s = 0.f;
  for (int r = r0; r < r0 + 100; ++r) s += part[(size_t)r * 256 + tid];
  atomicAdd(&stats[512 + tid], s);
}

// fold BN2 into W2, emit bf16 [o][c] weights + fp32 bias
__global__ void k_fold2(const float* __restrict__ W2, const float* __restrict__ b2,
                        const float* __restrict__ g2, const float* __restrict__ be2,
                        const float* __restrict__ stats,
                        unsigned short* __restrict__ W2bf, float* __restrict__ b2p) {
  __shared__ float red[Cc];
  int o = blockIdx.x, c = threadIdx.x;
  const float inv = 1.0f / (float)NE;
  float mu = stats[512 + c] * inv;
  float var = stats[640 + c] * inv - mu * mu;
  float a = g2[c] * rsqrtf(var + BN_EPS);
  float cc = be2[c] - mu * a;
  float w = W2[o * Cc + c];
  W2bf[o * Cc + c] = f2bf(w * a);
  red[c] = w * cc;
  __syncthreads();
  for (int s = 64; s > 0; s >>= 1) { if (c < s) red[c] += red[c + s]; __syncthreads(); }
  if (c == 0) b2p[o] = b2[o] + red[0];
}

// out[e][o] = relu( z[e]@W2' + b2' ): pure streaming bf16 MFMA GEMM.
// z read from the first 256 B of each out-row (loaded fully into registers
// before any store -> safe in-place overwrite). 64 edges x 128 outs, 4 waves.
#define WPAD 136
__global__ __launch_bounds__(256) void k_out_mfma(const unsigned short* __restrict__ zin,
                                                  const unsigned short* __restrict__ W2bf,
                                                  const float* __restrict__ b2p,
                                                  float* __restrict__ out) {
  __shared__ unsigned short Wl[128 * WPAD];  // 34816 B -> 4 blocks/CU
  int tid = threadIdx.x;
  int e0 = blockIdx.x * 64;

  // stage folded-bf16 W2 [o][c] -> LDS (coalesced 16B loads)
  for (int i = tid; i < 2048; i += 256) {
    int row = i >> 4, col = (i & 15) * 8;
    *(bf16x8*)&Wl[row * WPAD + col] = *(const bf16x8*)&W2bf[row * Cc + col];
  }

  int w = tid >> 6, l = tid & 63;
  int la = l & 15, kb = l >> 4;
  int e = e0 + w * 16 + la;

  // load all 4 A-fragments (full z row slice) into registers up front
  bf16x8 afr[4];
  #pragma unroll
  for (int kk = 0; kk < 4; ++kk)
    afr[kk] = *(const bf16x8*)&zin[(size_t)e * 256 + kk * 32 + kb * 8];
  __syncthreads();

  f32x4 acc[8];
  #pragma unroll
  for (int n = 0; n < 8; ++n) acc[n] = (f32x4){0.f, 0.f, 0.f, 0.f};

  #pragma unroll
  for (int kk = 0; kk < 4; ++kk) {        // K = 128 in 4 steps of 32
    #pragma unroll
    for (int n = 0; n < 8; ++n) {         // 8 out-tiles of 16
      bf16x8 b = *(const bf16x8*)&Wl[(n * 16 + la) * WPAD + kk * 32 + kb * 8];
      acc[n] = __builtin_amdgcn_mfma_f32_16x16x32_bf16(afr[kk], b, acc[n], 0, 0, 0);
    }
  }

  // C/D layout: col(out) = la, row(edge) = kb*4 + r  (verified epilogue)
  int r0 = kb * 4;
  #pragma unroll
  for (int n = 0; n < 8; ++n) {
    int col = n * 16 + la;
    float bb = b2p[col];
    #pragma unroll
    for (int r = 0; r < 4; ++r) {
      int eo = e0 + w * 16 + r0 + r;
      out[(size_t)eo * Cc + col] = fmaxf(acc[n][r] + bb, 0.f);
    }
  }
}

extern "C" void kernel_launch(void* const* d_in, const int* in_sizes, int n_in,
                              void* d_out, int out_size, void* d_ws, size_t ws_size,
                              hipStream_t stream) {
  (void)in_sizes; (void)n_in; (void)out_size; (void)ws_size;
  const float* x   = (const float*)d_in[0];
  const float* g1  = (const float*)d_in[1];
  const float* be1 = (const float*)d_in[2];
  const float* W1  = (const float*)d_in[3];
  const float* b1  = (const float*)d_in[4];
  const float* g2  = (const float*)d_in[5];
  const float* be2 = (const float*)d_in[6];
  const float* W2  = (const float*)d_in[7];
  const float* b2  = (const float*)d_in[8];
  const int* tgt   = (const int*)d_in[9];
  const int* src   = (const int*)d_in[10];

  float* ws  = (float*)d_ws;
  float* out = (float*)d_out;

  float* P     = ws + WS_P;
  float* Q     = ws + WS_Q;
  float* cntT  = ws + WS_CNTT;
  int*   cntS  = (int*)(ws + WS_CNTS);
  float* stats = ws + WS_STATS;
  float* W1pT  = ws + WS_W1PT;
  float* b1p   = ws + WS_B1P;
  unsigned short* W2bf = (unsigned short*)(ws + WS_W2BF);
  float* b2p   = ws + WS_B2P;
  float* part  = ws + WS_PART;
  float* nbr   = out;  // scratch: overwritten by k_stats2's z + k_out_mfma

  k_zero  <<<dim3((NN + 255) / 256), dim3(256), 0, stream>>>(stats, cntS);
  k_cnt   <<<dim3(NE / 256),        dim3(256), 0, stream>>>(src, cntS);
  k_nbr   <<<dim3(NN),              dim3(Cc),  0, stream>>>(x, tgt, src, nbr, cntT);
  k_stats1<<<dim3(256),             dim3(Cc),  0, stream>>>(nbr, x, cntT, cntS, stats);
  k_fold1 <<<dim3(Cc),              dim3(C2),  0, stream>>>(W1, b1, g1, be1, stats, W1pT, b1p);
  k_pq    <<<dim3(NN / 32, 2),      dim3(256), 0, stream>>>(nbr, x, W1pT, P, Q);
  k_stats2<<<dim3(NE / 256),        dim3(256), 0, stream>>>(P, Q, b1p, tgt, src,
                                                            (unsigned short*)out, part);
  k_red   <<<dim3(25),              dim3(256), 0, stream>>>(part, stats);
  k_fold2 <<<dim3(Cc),              dim3(Cc),  0, stream>>>(W2, b2, g2, be2, stats, W2bf, b2p);
  k_out_mfma<<<dim3(NE / 64),       dim3(256), 0, stream>>>((const unsigned short*)out,
                                                            W2bf, b2p, out);
}

// Round 13
// 376.245 us; speedup vs baseline: 1.1849x; 1.1849x over previous
//
#include <hip/hip_runtime.h>

#define NN 20000
#define NE 640000
#define Cc 128
#define C2 256
#define BN_EPS 1e-5f

typedef __attribute__((ext_vector_type(8))) short bf16x8;
typedef __attribute__((ext_vector_type(4))) float f32x4;

// ---- workspace layout (float offsets) ----
#define WS_P     0                      // [NN*Cc]
#define WS_Q     (NN*Cc)                // [NN*Cc]
#define WS_CNTT  (2*NN*Cc)              // [NN] float
#define WS_CNTS  (2*NN*Cc + NN)         // [NN] int
#define WS_STATS (2*NN*Cc + 2*NN)       // [768]: sum1[256], sq1[256], sum2[128], sq2[128]
#define WS_W1PT  (WS_STATS + 768)       // [256*128] transposed folded W1: [c][o]
#define WS_B1P   (WS_W1PT + C2*Cc)      // [128]
#define WS_W2BF  (WS_B1P + Cc)          // ushort[128*128] folded W2 bf16: [o][c]
#define WS_B2P   (WS_W2BF + Cc*Cc)      // [128]

// z (bf16) for edge e lives in the FIRST 256 B of out-row e's 512 B slot:
// ushort index e*256 + c. Written by k_stats2, read (then overwritten) by
// k_out_mfma's own wave -> no race (reads complete into regs before stores).

// fp32 -> bf16 round-to-nearest-even
static __device__ inline unsigned short f2bf(float f) {
  union { float f; unsigned u; } v; v.f = f;
  unsigned r = v.u + 0x7fffu + ((v.u >> 16) & 1u);
  return (unsigned short)(r >> 16);
}

__global__ void k_zero(float* __restrict__ stats, int* __restrict__ cntS) {
  int i = blockIdx.x * blockDim.x + threadIdx.x;
  if (i < 768) stats[i] = 0.0f;
  if (i < NN) cntS[i] = 0;
}

__global__ void k_cnt(const int* __restrict__ src, int* __restrict__ cntS) {
  int e = blockIdx.x * blockDim.x + threadIdx.x;
  if (e < NE) atomicAdd(&cntS[src[e]], 1);
}

// one block (128 threads) per node: segment sum of x[src] over the node's
// contiguous (tgt sorted) edge range, found by binary search.
__global__ void k_nbr(const float* __restrict__ x, const int* __restrict__ tgt,
                      const int* __restrict__ src, float* __restrict__ nbr,
                      float* __restrict__ cntT) {
  int node = blockIdx.x;
  int a = 0, b = NE;
  while (a < b) { int m = (a + b) >> 1; if (tgt[m] < node) a = m + 1; else b = m; }
  int lo = a;
  b = NE;
  while (a < b) { int m = (a + b) >> 1; if (tgt[m] <= node) a = m + 1; else b = m; }
  int hi = a;
  int c = threadIdx.x;
  float acc = 0.0f;
  for (int e = lo; e < hi; ++e) acc += x[src[e] * Cc + c];
  nbr[node * Cc + c] = acc;
  if (c == 0) cntT[node] = (float)(hi - lo);
}

// BN1 stats: count-weighted sums over nodes.
__global__ void k_stats1(const float* __restrict__ nbr, const float* __restrict__ x,
                         const float* __restrict__ cntT, const int* __restrict__ cntS,
                         float* __restrict__ stats) {
  int c = threadIdx.x;
  float sa = 0.f, qa = 0.f, sb = 0.f, qb = 0.f;
  for (int t = blockIdx.x; t < NN; t += gridDim.x) {
    float ct = cntT[t];
    float cs = (float)cntS[t];
    float v1 = nbr[t * Cc + c];
    float v2 = x[t * Cc + c];
    sa += ct * v1; qa += ct * v1 * v1;
    sb += cs * v2; qb += cs * v2 * v2;
  }
  atomicAdd(&stats[c], sa);
  atomicAdd(&stats[256 + c], qa);
  atomicAdd(&stats[128 + c], sb);
  atomicAdd(&stats[256 + 128 + c], qb);
}

// fold BN1 into W1: W1pT[c][o] = W1[o][c]*a1[c];  b1p[o] = b1[o] + sum_c W1[o][c]*c1[c]
__global__ void k_fold1(const float* __restrict__ W1, const float* __restrict__ b1,
                        const float* __restrict__ g1, const float* __restrict__ be1,
                        const float* __restrict__ stats,
                        float* __restrict__ W1pT, float* __restrict__ b1p) {
  __shared__ float red[C2];
  int o = blockIdx.x, c = threadIdx.x;
  const float inv = 1.0f / (float)NE;
  float mu = stats[c] * inv;
  float var = stats[256 + c] * inv - mu * mu;
  float a = g1[c] * rsqrtf(var + BN_EPS);
  float cc = be1[c] - mu * a;
  float w = W1[o * C2 + c];
  W1pT[c * Cc + o] = w * a;
  red[c] = w * cc;
  __syncthreads();
  for (int s = 128; s > 0; s >>= 1) { if (c < s) red[c] += red[c + s]; __syncthreads(); }
  if (c == 0) b1p[o] = b1[o] + red[0];
}

// P = nbr_sum @ W1a'.T ; Q = x @ W1b'.T   (blockIdx.y selects half)
__global__ __launch_bounds__(256) void k_pq(const float* __restrict__ nbr,
                                            const float* __restrict__ x,
                                            const float* __restrict__ W1pT,
                                            float* __restrict__ P,
                                            float* __restrict__ Q) {
  __shared__ float Ar[32][128];
  const int half = blockIdx.y;
  const float* __restrict__ A = half ? x : nbr;
  float* __restrict__ Out = half ? Q : P;
  const float* __restrict__ Wt = W1pT + (half ? Cc * Cc : 0);  // [128 c][128 o]
  int tid = threadIdx.x;
  int r0 = blockIdx.x * 32;
  for (int i = tid; i < 32 * 128; i += 256) {
    int r = i >> 7, c = i & 127;
    Ar[r][c] = A[(r0 + r) * Cc + c];
  }
  __syncthreads();
  int tx = tid & 31, ty = tid >> 5;
  float acc[4][4] = {};
  #pragma unroll 4
  for (int c = 0; c < 128; ++c) {
    float4 w = *(const float4*)&Wt[c * Cc + tx * 4];
    float a0 = Ar[ty * 4 + 0][c], a1 = Ar[ty * 4 + 1][c];
    float a2 = Ar[ty * 4 + 2][c], a3 = Ar[ty * 4 + 3][c];
    acc[0][0] += a0 * w.x; acc[0][1] += a0 * w.y; acc[0][2] += a0 * w.z; acc[0][3] += a0 * w.w;
    acc[1][0] += a1 * w.x; acc[1][1] += a1 * w.y; acc[1][2] += a1 * w.z; acc[1][3] += a1 * w.w;
    acc[2][0] += a2 * w.x; acc[2][1] += a2 * w.y; acc[2][2] += a2 * w.z; acc[2][3] += a2 * w.w;
    acc[3][0] += a3 * w.x; acc[3][1] += a3 * w.y; acc[3][2] += a3 * w.z; acc[3][3] += a3 * w.w;
  }
  #pragma unroll
  for (int i = 0; i < 4; ++i) {
    int node = r0 + ty * 4 + i;
    float4 v = make_float4(acc[i][0], acc[i][1], acc[i][2], acc[i][3]);
    *(float4*)&Out[node * Cc + tx * 4] = v;
  }
}

// BN2 stats + z materialization (round-11 structure: 1250 blocks x 128 thr,
// 512 consecutive edges/block -> sorted-tgt P-row locality) with explicit
// 8-deep unroll: 16 index + 16 P/Q loads in flight to break the
// load->load latency chain (measured ~630 cyc/edge without it).
__global__ void k_stats2(const float* __restrict__ P, const float* __restrict__ Q,
                         const float* __restrict__ b1p,
                         const int* __restrict__ tgt, const int* __restrict__ src,
                         float* __restrict__ stats, unsigned short* __restrict__ zout) {
  int c = threadIdx.x;
  int e0 = blockIdx.x * 512;
  float b = b1p[c];
  float s = 0.f, q = 0.f;
  for (int e = e0; e < e0 + 512; e += 8) {
    int t[8], sr[8];
    #pragma unroll
    for (int j = 0; j < 8; ++j) { t[j] = tgt[e + j]; sr[j] = src[e + j]; }
    float pv[8], qv[8];
    #pragma unroll
    for (int j = 0; j < 8; ++j) pv[j] = P[(size_t)t[j] * Cc + c];
    #pragma unroll
    for (int j = 0; j < 8; ++j) qv[j] = Q[(size_t)sr[j] * Cc + c];
    float z[8];
    #pragma unroll
    for (int j = 0; j < 8; ++j) {
      z[j] = fmaxf(pv[j] + qv[j] + b, 0.f);
      zout[(size_t)(e + j) * 256 + c] = f2bf(z[j]);
    }
    s += ((z[0] + z[1]) + (z[2] + z[3])) + ((z[4] + z[5]) + (z[6] + z[7]));
    q += ((z[0]*z[0] + z[1]*z[1]) + (z[2]*z[2] + z[3]*z[3]))
       + ((z[4]*z[4] + z[5]*z[5]) + (z[6]*z[6] + z[7]*z[7]));
  }
  atomicAdd(&stats[512 + c], s);
  atomicAdd(&stats[640 + c], q);
}

// fold BN2 into W2, emit bf16 [o][c] weights + fp32 bias
__global__ void k_fold2(const float* __restrict__ W2, const float* __restrict__ b2,
                        const float* __restrict__ g2, const float* __restrict__ be2,
                        const float* __restrict__ stats,
                        unsigned short* __restrict__ W2bf, float* __restrict__ b2p) {
  __shared__ float red[Cc];
  int o = blockIdx.x, c = threadIdx.x;
  const float inv = 1.0f / (float)NE;
  float mu = stats[512 + c] * inv;
  float var = stats[640 + c] * inv - mu * mu;
  float a = g2[c] * rsqrtf(var + BN_EPS);
  float cc = be2[c] - mu * a;
  float w = W2[o * Cc + c];
  W2bf[o * Cc + c] = f2bf(w * a);
  red[c] = w * cc;
  __syncthreads();
  for (int s = 64; s > 0; s >>= 1) { if (c < s) red[c] += red[c + s]; __syncthreads(); }
  if (c == 0) b2p[o] = b2[o] + red[0];
}

// out[e][o] = relu( z[e]@W2' + b2' ): pure streaming bf16 MFMA GEMM.
// z read from the first 256 B of each out-row (loaded fully into registers
// before any store -> safe in-place overwrite). 64 edges x 128 outs, 4 waves.
#define WPAD 136
__global__ __launch_bounds__(256) void k_out_mfma(const unsigned short* __restrict__ zin,
                                                  const unsigned short* __restrict__ W2bf,
                                                  const float* __restrict__ b2p,
                                                  float* __restrict__ out) {
  __shared__ unsigned short Wl[128 * WPAD];  // 34816 B -> 4 blocks/CU
  int tid = threadIdx.x;
  int e0 = blockIdx.x * 64;

  // stage folded-bf16 W2 [o][c] -> LDS (coalesced 16B loads)
  for (int i = tid; i < 2048; i += 256) {
    int row = i >> 4, col = (i & 15) * 8;
    *(bf16x8*)&Wl[row * WPAD + col] = *(const bf16x8*)&W2bf[row * Cc + col];
  }

  int w = tid >> 6, l = tid & 63;
  int la = l & 15, kb = l >> 4;
  int e = e0 + w * 16 + la;

  // load all 4 A-fragments (full z row slice) into registers up front
  bf16x8 afr[4];
  #pragma unroll
  for (int kk = 0; kk < 4; ++kk)
    afr[kk] = *(const bf16x8*)&zin[(size_t)e * 256 + kk * 32 + kb * 8];
  __syncthreads();

  f32x4 acc[8];
  #pragma unroll
  for (int n = 0; n < 8; ++n) acc[n] = (f32x4){0.f, 0.f, 0.f, 0.f};

  #pragma unroll
  for (int kk = 0; kk < 4; ++kk) {        // K = 128 in 4 steps of 32
    #pragma unroll
    for (int n = 0; n < 8; ++n) {         // 8 out-tiles of 16
      bf16x8 b = *(const bf16x8*)&Wl[(n * 16 + la) * WPAD + kk * 32 + kb * 8];
      acc[n] = __builtin_amdgcn_mfma_f32_16x16x32_bf16(afr[kk], b, acc[n], 0, 0, 0);
    }
  }

  // C/D layout: col(out) = la, row(edge) = kb*4 + r  (verified epilogue)
  int r0 = kb * 4;
  #pragma unroll
  for (int n = 0; n < 8; ++n) {
    int col = n * 16 + la;
    float bb = b2p[col];
    #pragma unroll
    for (int r = 0; r < 4; ++r) {
      int eo = e0 + w * 16 + r0 + r;
      out[(size_t)eo * Cc + col] = fmaxf(acc[n][r] + bb, 0.f);
    }
  }
}

extern "C" void kernel_launch(void* const* d_in, const int* in_sizes, int n_in,
                              void* d_out, int out_size, void* d_ws, size_t ws_size,
                              hipStream_t stream) {
  (void)in_sizes; (void)n_in; (void)out_size; (void)ws_size;
  const float* x   = (const float*)d_in[0];
  const float* g1  = (const float*)d_in[1];
  const float* be1 = (const float*)d_in[2];
  const float* W1  = (const float*)d_in[3];
  const float* b1  = (const float*)d_in[4];
  const float* g2  = (const float*)d_in[5];
  const float* be2 = (const float*)d_in[6];
  const float* W2  = (const float*)d_in[7];
  const float* b2  = (const float*)d_in[8];
  const int* tgt   = (const int*)d_in[9];
  const int* src   = (const int*)d_in[10];

  float* ws  = (float*)d_ws;
  float* out = (float*)d_out;

  float* P     = ws + WS_P;
  float* Q     = ws + WS_Q;
  float* cntT  = ws + WS_CNTT;
  int*   cntS  = (int*)(ws + WS_CNTS);
  float* stats = ws + WS_STATS;
  float* W1pT  = ws + WS_W1PT;
  float* b1p   = ws + WS_B1P;
  unsigned short* W2bf = (unsigned short*)(ws + WS_W2BF);
  float* b2p   = ws + WS_B2P;
  float* nbr   = out;  // scratch: overwritten by k_stats2's z + k_out_mfma

  k_zero  <<<dim3((NN + 255) / 256), dim3(256), 0, stream>>>(stats, cntS);
  k_cnt   <<<dim3(NE / 256),        dim3(256), 0, stream>>>(src, cntS);
  k_nbr   <<<dim3(NN),              dim3(Cc),  0, stream>>>(x, tgt, src, nbr, cntT);
  k_stats1<<<dim3(256),             dim3(Cc),  0, stream>>>(nbr, x, cntT, cntS, stats);
  k_fold1 <<<dim3(Cc),              dim3(C2),  0, stream>>>(W1, b1, g1, be1, stats, W1pT, b1p);
  k_pq    <<<dim3(NN / 32, 2),      dim3(256), 0, stream>>>(nbr, x, W1pT, P, Q);
  k_stats2<<<dim3(NE / 512),        dim3(Cc),  0, stream>>>(P, Q, b1p, tgt, src, stats,
                                                            (unsigned short*)out);
  k_fold2 <<<dim3(Cc),              dim3(Cc),  0, stream>>>(W2, b2, g2, be2, stats, W2bf, b2p);
  k_out_mfma<<<dim3(NE / 64),       dim3(256), 0, stream>>>((const unsigned short*)out,
                                                            W2bf, b2p, out);
}

// Round 14
// 339.206 us; speedup vs baseline: 1.3142x; 1.1092x over previous
//
#include <hip/hip_runtime.h>

#define NN 20000
#define NE 640000
#define Cc 128
#define C2 256
#define BN_EPS 1e-5f

typedef __attribute__((ext_vector_type(8))) short bf16x8;
typedef __attribute__((ext_vector_type(4))) float f32x4;

// ---- workspace layout (float offsets) ----
#define WS_P     0                      // [NN*Cc]
#define WS_Q     (NN*Cc)                // [NN*Cc]
#define WS_CNTT  (2*NN*Cc)              // [NN] float
#define WS_CNTS  (2*NN*Cc + NN)         // [NN] int
#define WS_STATS (2*NN*Cc + 2*NN)       // [768]: sum1[256], sq1[256], sum2[128], sq2[128]
#define WS_W1PT  (WS_STATS + 768)       // [256*128] transposed folded W1: [c][o]
#define WS_B1P   (WS_W1PT + C2*Cc)      // [128]
#define WS_W2BF  (WS_B1P + Cc)          // ushort[128*128] folded W2 bf16: [o][c]
#define WS_B2P   (WS_W2BF + Cc*Cc)      // [128]

// z (bf16) for edge e lives in the FIRST 256 B of out-row e's 512 B slot:
// ushort index e*256 + c. Written by k_stats2, read (then overwritten) by
// k_out_mfma's own wave -> no race (reads complete into regs before stores).

// fp32 -> bf16 round-to-nearest-even
static __device__ inline unsigned short f2bf(float f) {
  union { float f; unsigned u; } v; v.f = f;
  unsigned r = v.u + 0x7fffu + ((v.u >> 16) & 1u);
  return (unsigned short)(r >> 16);
}

__global__ void k_zero(float* __restrict__ stats, int* __restrict__ cntS) {
  int i = blockIdx.x * blockDim.x + threadIdx.x;
  if (i < 768) stats[i] = 0.0f;
  if (i < NN) cntS[i] = 0;
}

__global__ void k_cnt(const int* __restrict__ src, int* __restrict__ cntS) {
  int e = blockIdx.x * blockDim.x + threadIdx.x;
  if (e < NE) atomicAdd(&cntS[src[e]], 1);
}

// one block (128 threads) per node: segment sum of x[src] over the node's
// contiguous (tgt sorted) edge range; 4-deep unroll for gather ILP.
__global__ void k_nbr(const float* __restrict__ x, const int* __restrict__ tgt,
                      const int* __restrict__ src, float* __restrict__ nbr,
                      float* __restrict__ cntT) {
  int node = blockIdx.x;
  int a = 0, b = NE;
  while (a < b) { int m = (a + b) >> 1; if (tgt[m] < node) a = m + 1; else b = m; }
  int lo = a;
  b = NE;
  while (a < b) { int m = (a + b) >> 1; if (tgt[m] <= node) a = m + 1; else b = m; }
  int hi = a;
  int c = threadIdx.x;
  float a0 = 0.f, a1 = 0.f, a2 = 0.f, a3 = 0.f;
  int e = lo;
  for (; e + 3 < hi; e += 4) {
    int s0 = src[e], s1 = src[e + 1], s2 = src[e + 2], s3 = src[e + 3];
    a0 += x[(size_t)s0 * Cc + c];
    a1 += x[(size_t)s1 * Cc + c];
    a2 += x[(size_t)s2 * Cc + c];
    a3 += x[(size_t)s3 * Cc + c];
  }
  for (; e < hi; ++e) a0 += x[(size_t)src[e] * Cc + c];
  nbr[node * Cc + c] = (a0 + a1) + (a2 + a3);
  if (c == 0) cntT[node] = (float)(hi - lo);
}

// BN1 stats: count-weighted sums over nodes.
__global__ void k_stats1(const float* __restrict__ nbr, const float* __restrict__ x,
                         const float* __restrict__ cntT, const int* __restrict__ cntS,
                         float* __restrict__ stats) {
  int c = threadIdx.x;
  float sa = 0.f, qa = 0.f, sb = 0.f, qb = 0.f;
  for (int t = blockIdx.x; t < NN; t += gridDim.x) {
    float ct = cntT[t];
    float cs = (float)cntS[t];
    float v1 = nbr[t * Cc + c];
    float v2 = x[t * Cc + c];
    sa += ct * v1; qa += ct * v1 * v1;
    sb += cs * v2; qb += cs * v2 * v2;
  }
  atomicAdd(&stats[c], sa);
  atomicAdd(&stats[256 + c], qa);
  atomicAdd(&stats[128 + c], sb);
  atomicAdd(&stats[256 + 128 + c], qb);
}

// fold BN1 into W1: W1pT[c][o] = W1[o][c]*a1[c];  b1p[o] = b1[o] + sum_c W1[o][c]*c1[c]
__global__ void k_fold1(const float* __restrict__ W1, const float* __restrict__ b1,
                        const float* __restrict__ g1, const float* __restrict__ be1,
                        const float* __restrict__ stats,
                        float* __restrict__ W1pT, float* __restrict__ b1p) {
  __shared__ float red[C2];
  int o = blockIdx.x, c = threadIdx.x;
  const float inv = 1.0f / (float)NE;
  float mu = stats[c] * inv;
  float var = stats[256 + c] * inv - mu * mu;
  float a = g1[c] * rsqrtf(var + BN_EPS);
  float cc = be1[c] - mu * a;
  float w = W1[o * C2 + c];
  W1pT[c * Cc + o] = w * a;
  red[c] = w * cc;
  __syncthreads();
  for (int s = 128; s > 0; s >>= 1) { if (c < s) red[c] += red[c + s]; __syncthreads(); }
  if (c == 0) b1p[o] = b1[o] + red[0];
}

// P = nbr_sum @ W1a'.T ; Q = x @ W1b'.T   (blockIdx.y selects half)
__global__ __launch_bounds__(256) void k_pq(const float* __restrict__ nbr,
                                            const float* __restrict__ x,
                                            const float* __restrict__ W1pT,
                                            float* __restrict__ P,
                                            float* __restrict__ Q) {
  __shared__ float Ar[32][128];
  const int half = blockIdx.y;
  const float* __restrict__ A = half ? x : nbr;
  float* __restrict__ Out = half ? Q : P;
  const float* __restrict__ Wt = W1pT + (half ? Cc * Cc : 0);  // [128 c][128 o]
  int tid = threadIdx.x;
  int r0 = blockIdx.x * 32;
  for (int i = tid; i < 32 * 128; i += 256) {
    int r = i >> 7, c = i & 127;
    Ar[r][c] = A[(r0 + r) * Cc + c];
  }
  __syncthreads();
  int tx = tid & 31, ty = tid >> 5;
  float acc[4][4] = {};
  #pragma unroll 4
  for (int c = 0; c < 128; ++c) {
    float4 w = *(const float4*)&Wt[c * Cc + tx * 4];
    float a0 = Ar[ty * 4 + 0][c], a1 = Ar[ty * 4 + 1][c];
    float a2 = Ar[ty * 4 + 2][c], a3 = Ar[ty * 4 + 3][c];
    acc[0][0] += a0 * w.x; acc[0][1] += a0 * w.y; acc[0][2] += a0 * w.z; acc[0][3] += a0 * w.w;
    acc[1][0] += a1 * w.x; acc[1][1] += a1 * w.y; acc[1][2] += a1 * w.z; acc[1][3] += a1 * w.w;
    acc[2][0] += a2 * w.x; acc[2][1] += a2 * w.y; acc[2][2] += a2 * w.z; acc[2][3] += a2 * w.w;
    acc[3][0] += a3 * w.x; acc[3][1] += a3 * w.y; acc[3][2] += a3 * w.z; acc[3][3] += a3 * w.w;
  }
  #pragma unroll
  for (int i = 0; i < 4; ++i) {
    int node = r0 + ty * 4 + i;
    float4 v = make_float4(acc[i][0], acc[i][1], acc[i][2], acc[i][3]);
    *(float4*)&Out[node * Cc + tx * 4] = v;
  }
}

// BN2 stats + z materialization. 1250 blocks x 256 threads: two half-wave
// stripes (y=0/1) interleave by OCTETS within the same 512-edge sorted-tgt
// window -> P-locality kept, occupancy 2x, 8-deep gather ILP kept.
// LDS-combine partials; 1 atomic per channel per block (unchanged count).
__global__ __launch_bounds__(256) void k_stats2(const float* __restrict__ P,
                                                const float* __restrict__ Q,
                                                const float* __restrict__ b1p,
                                                const int* __restrict__ tgt,
                                                const int* __restrict__ src,
                                                float* __restrict__ stats,
                                                unsigned short* __restrict__ zout) {
  __shared__ float s2[Cc], q2[Cc];
  int c = threadIdx.x & 127;
  int y = threadIdx.x >> 7;
  int e0 = blockIdx.x * 512;
  float b = b1p[c];
  float s = 0.f, q = 0.f;
  for (int e = e0 + y * 8; e < e0 + 512; e += 16) {
    int t[8], sr[8];
    #pragma unroll
    for (int j = 0; j < 8; ++j) { t[j] = tgt[e + j]; sr[j] = src[e + j]; }
    float pv[8], qv[8];
    #pragma unroll
    for (int j = 0; j < 8; ++j) pv[j] = P[(size_t)t[j] * Cc + c];
    #pragma unroll
    for (int j = 0; j < 8; ++j) qv[j] = Q[(size_t)sr[j] * Cc + c];
    float z[8];
    #pragma unroll
    for (int j = 0; j < 8; ++j) {
      z[j] = fmaxf(pv[j] + qv[j] + b, 0.f);
      zout[(size_t)(e + j) * 256 + c] = f2bf(z[j]);
    }
    s += ((z[0] + z[1]) + (z[2] + z[3])) + ((z[4] + z[5]) + (z[6] + z[7]));
    q += ((z[0]*z[0] + z[1]*z[1]) + (z[2]*z[2] + z[3]*z[3]))
       + ((z[4]*z[4] + z[5]*z[5]) + (z[6]*z[6] + z[7]*z[7]));
  }
  if (y) { s2[c] = s; q2[c] = q; }
  __syncthreads();
  if (!y) {
    atomicAdd(&stats[512 + c], s + s2[c]);
    atomicAdd(&stats[640 + c], q + q2[c]);
  }
}

// fold BN2 into W2, emit bf16 [o][c] weights + fp32 bias
__global__ void k_fold2(const float* __restrict__ W2, const float* __restrict__ b2,
                        const float* __restrict__ g2, const float* __restrict__ be2,
                        const float* __restrict__ stats,
                        unsigned short* __restrict__ W2bf, float* __restrict__ b2p) {
  __shared__ float red[Cc];
  int o = blockIdx.x, c = threadIdx.x;
  const float inv = 1.0f / (float)NE;
  float mu = stats[512 + c] * inv;
  float var = stats[640 + c] * inv - mu * mu;
  float a = g2[c] * rsqrtf(var + BN_EPS);
  float cc = be2[c] - mu * a;
  float w = W2[o * Cc + c];
  W2bf[o * Cc + c] = f2bf(w * a);
  red[c] = w * cc;
  __syncthreads();
  for (int s = 64; s > 0; s >>= 1) { if (c < s) red[c] += red[c + s]; __syncthreads(); }
  if (c == 0) b2p[o] = b2[o] + red[0];
}

// out[e][o] = relu( z[e]@W2' + b2' ): pure streaming bf16 MFMA GEMM.
// z read from the first 256 B of each out-row (loaded fully into registers
// before any store -> safe in-place overwrite). 64 edges x 128 outs, 4 waves.
#define WPAD 136
__global__ __launch_bounds__(256) void k_out_mfma(const unsigned short* __restrict__ zin,
                                                  const unsigned short* __restrict__ W2bf,
                                                  const float* __restrict__ b2p,
                                                  float* __restrict__ out) {
  __shared__ unsigned short Wl[128 * WPAD];  // 34816 B -> 4 blocks/CU
  int tid = threadIdx.x;
  int e0 = blockIdx.x * 64;

  // stage folded-bf16 W2 [o][c] -> LDS (coalesced 16B loads)
  for (int i = tid; i < 2048; i += 256) {
    int row = i >> 4, col = (i & 15) * 8;
    *(bf16x8*)&Wl[row * WPAD + col] = *(const bf16x8*)&W2bf[row * Cc + col];
  }

  int w = tid >> 6, l = tid & 63;
  int la = l & 15, kb = l >> 4;
  int e = e0 + w * 16 + la;

  // load all 4 A-fragments (full z row slice) into registers up front
  bf16x8 afr[4];
  #pragma unroll
  for (int kk = 0; kk < 4; ++kk)
    afr[kk] = *(const bf16x8*)&zin[(size_t)e * 256 + kk * 32 + kb * 8];
  __syncthreads();

  f32x4 acc[8];
  #pragma unroll
  for (int n = 0; n < 8; ++n) acc[n] = (f32x4){0.f, 0.f, 0.f, 0.f};

  #pragma unroll
  for (int kk = 0; kk < 4; ++kk) {        // K = 128 in 4 steps of 32
    #pragma unroll
    for (int n = 0; n < 8; ++n) {         // 8 out-tiles of 16
      bf16x8 b = *(const bf16x8*)&Wl[(n * 16 + la) * WPAD + kk * 32 + kb * 8];
      acc[n] = __builtin_amdgcn_mfma_f32_16x16x32_bf16(afr[kk], b, acc[n], 0, 0, 0);
    }
  }

  // C/D layout: col(out) = la, row(edge) = kb*4 + r  (verified epilogue)
  int r0 = kb * 4;
  #pragma unroll
  for (int n = 0; n < 8; ++n) {
    int col = n * 16 + la;
    float bb = b2p[col];
    #pragma unroll
    for (int r = 0; r < 4; ++r) {
      int eo = e0 + w * 16 + r0 + r;
      out[(size_t)eo * Cc + col] = fmaxf(acc[n][r] + bb, 0.f);
    }
  }
}

extern "C" void kernel_launch(void* const* d_in, const int* in_sizes, int n_in,
                              void* d_out, int out_size, void* d_ws, size_t ws_size,
                              hipStream_t stream) {
  (void)in_sizes; (void)n_in; (void)out_size; (void)ws_size;
  const float* x   = (const float*)d_in[0];
  const float* g1  = (const float*)d_in[1];
  const float* be1 = (const float*)d_in[2];
  const float* W1  = (const float*)d_in[3];
  const float* b1  = (const float*)d_in[4];
  const float* g2  = (const float*)d_in[5];
  const float* be2 = (const float*)d_in[6];
  const float* W2  = (const float*)d_in[7];
  const float* b2  = (const float*)d_in[8];
  const int* tgt   = (const int*)d_in[9];
  const int* src   = (const int*)d_in[10];

  float* ws  = (float*)d_ws;
  float* out = (float*)d_out;

  float* P     = ws + WS_P;
  float* Q     = ws + WS_Q;
  float* cntT  = ws + WS_CNTT;
  int*   cntS  = (int*)(ws + WS_CNTS);
  float* stats = ws + WS_STATS;
  float* W1pT  = ws + WS_W1PT;
  float* b1p   = ws + WS_B1P;
  unsigned short* W2bf = (unsigned short*)(ws + WS_W2BF);
  float* b2p   = ws + WS_B2P;
  float* nbr   = out;  // scratch: overwritten by k_stats2's z + k_out_mfma

  k_zero  <<<dim3((NN + 255) / 256), dim3(256), 0, stream>>>(stats, cntS);
  k_cnt   <<<dim3(NE / 256),        dim3(256), 0, stream>>>(src, cntS);
  k_nbr   <<<dim3(NN),              dim3(Cc),  0, stream>>>(x, tgt, src, nbr, cntT);
  k_stats1<<<dim3(256),             dim3(Cc),  0, stream>>>(nbr, x, cntT, cntS, stats);
  k_fold1 <<<dim3(Cc),              dim3(C2),  0, stream>>>(W1, b1, g1, be1, stats, W1pT, b1p);
  k_pq    <<<dim3(NN / 32, 2),      dim3(256), 0, stream>>>(nbr, x, W1pT, P, Q);
  k_stats2<<<dim3(NE / 512),        dim3(256), 0, stream>>>(P, Q, b1p, tgt, src, stats,
                                                            (unsigned short*)out);
  k_fold2 <<<dim3(Cc),              dim3(Cc),  0, stream>>>(W2, b2, g2, be2, stats, W2bf, b2p);
  k_out_mfma<<<dim3(NE / 64),       dim3(256), 0, stream>>>((const unsigned short*)out,
                                                            W2bf, b2p, out);
}

// Round 15
// 324.870 us; speedup vs baseline: 1.3722x; 1.0441x over previous
//
#include <hip/hip_runtime.h>

#define NN 20000
#define NE 640000
#define Cc 128
#define C2 256
#define BN_EPS 1e-5f

typedef __attribute__((ext_vector_type(8))) short bf16x8;
typedef __attribute__((ext_vector_type(4))) float f32x4;

// ---- workspace layout (float offsets) ----
#define WS_P     0                      // [NN*Cc]
#define WS_Q     (NN*Cc)                // [NN*Cc]
#define WS_CNTT  (2*NN*Cc)              // [NN] float
#define WS_CNTS  (2*NN*Cc + NN)         // [NN] int
#define WS_STATS (2*NN*Cc + 2*NN)       // [768]: sum1[256], sq1[256], sum2[128], sq2[128]
#define WS_W1PT  (WS_STATS + 768)       // [256*128] transposed folded W1: [c][o]
#define WS_B1P   (WS_W1PT + C2*Cc)      // [128]
#define WS_W2BF  (WS_B1P + Cc)          // ushort[128*128] folded W2 bf16: [o][c]
#define WS_B2P   (WS_W2BF + Cc*Cc)      // [128]

// z (bf16) for edge e lives in the FIRST 256 B of out-row e's 512 B slot:
// ushort index e*256 + c. Written by k_stats2, read (then overwritten) by
// k_out_mfma's own wave -> no race (reads complete into regs before stores).

// fp32 -> bf16 round-to-nearest-even
static __device__ inline unsigned short f2bf(float f) {
  union { float f; unsigned u; } v; v.f = f;
  unsigned r = v.u + 0x7fffu + ((v.u >> 16) & 1u);
  return (unsigned short)(r >> 16);
}

__global__ void k_zero(float* __restrict__ stats, int* __restrict__ cntS) {
  int i = blockIdx.x * blockDim.x + threadIdx.x;
  if (i < 768) stats[i] = 0.0f;
  if (i < NN) cntS[i] = 0;
}

__global__ void k_cnt(const int* __restrict__ src, int* __restrict__ cntS) {
  int e = blockIdx.x * blockDim.x + threadIdx.x;
  if (e < NE) atomicAdd(&cntS[src[e]], 1);
}

// one block (128 threads) per node: segment sum of x[src] over the node's
// contiguous (tgt sorted) edge range; 4-deep unroll for gather ILP.
__global__ void k_nbr(const float* __restrict__ x, const int* __restrict__ tgt,
                      const int* __restrict__ src, float* __restrict__ nbr,
                      float* __restrict__ cntT) {
  int node = blockIdx.x;
  int a = 0, b = NE;
  while (a < b) { int m = (a + b) >> 1; if (tgt[m] < node) a = m + 1; else b = m; }
  int lo = a;
  b = NE;
  while (a < b) { int m = (a + b) >> 1; if (tgt[m] <= node) a = m + 1; else b = m; }
  int hi = a;
  int c = threadIdx.x;
  float a0 = 0.f, a1 = 0.f, a2 = 0.f, a3 = 0.f;
  int e = lo;
  for (; e + 3 < hi; e += 4) {
    int s0 = src[e], s1 = src[e + 1], s2 = src[e + 2], s3 = src[e + 3];
    a0 += x[(size_t)s0 * Cc + c];
    a1 += x[(size_t)s1 * Cc + c];
    a2 += x[(size_t)s2 * Cc + c];
    a3 += x[(size_t)s3 * Cc + c];
  }
  for (; e < hi; ++e) a0 += x[(size_t)src[e] * Cc + c];
  nbr[node * Cc + c] = (a0 + a1) + (a2 + a3);
  if (c == 0) cntT[node] = (float)(hi - lo);
}

// BN1 stats: count-weighted sums over nodes.
__global__ void k_stats1(const float* __restrict__ nbr, const float* __restrict__ x,
                         const float* __restrict__ cntT, const int* __restrict__ cntS,
                         float* __restrict__ stats) {
  int c = threadIdx.x;
  float sa = 0.f, qa = 0.f, sb = 0.f, qb = 0.f;
  for (int t = blockIdx.x; t < NN; t += gridDim.x) {
    float ct = cntT[t];
    float cs = (float)cntS[t];
    float v1 = nbr[t * Cc + c];
    float v2 = x[t * Cc + c];
    sa += ct * v1; qa += ct * v1 * v1;
    sb += cs * v2; qb += cs * v2 * v2;
  }
  atomicAdd(&stats[c], sa);
  atomicAdd(&stats[256 + c], qa);
  atomicAdd(&stats[128 + c], sb);
  atomicAdd(&stats[256 + 128 + c], qb);
}

// fold BN1 into W1: W1pT[c][o] = W1[o][c]*a1[c];  b1p[o] = b1[o] + sum_c W1[o][c]*c1[c]
__global__ void k_fold1(const float* __restrict__ W1, const float* __restrict__ b1,
                        const float* __restrict__ g1, const float* __restrict__ be1,
                        const float* __restrict__ stats,
                        float* __restrict__ W1pT, float* __restrict__ b1p) {
  __shared__ float red[C2];
  int o = blockIdx.x, c = threadIdx.x;
  const float inv = 1.0f / (float)NE;
  float mu = stats[c] * inv;
  float var = stats[256 + c] * inv - mu * mu;
  float a = g1[c] * rsqrtf(var + BN_EPS);
  float cc = be1[c] - mu * a;
  float w = W1[o * C2 + c];
  W1pT[c * Cc + o] = w * a;
  red[c] = w * cc;
  __syncthreads();
  for (int s = 128; s > 0; s >>= 1) { if (c < s) red[c] += red[c + s]; __syncthreads(); }
  if (c == 0) b1p[o] = b1[o] + red[0];
}

// P = nbr_sum @ W1a'.T ; Q = x @ W1b'.T   (blockIdx.y selects half)
__global__ __launch_bounds__(256) void k_pq(const float* __restrict__ nbr,
                                            const float* __restrict__ x,
                                            const float* __restrict__ W1pT,
                                            float* __restrict__ P,
                                            float* __restrict__ Q) {
  __shared__ float Ar[32][128];
  const int half = blockIdx.y;
  const float* __restrict__ A = half ? x : nbr;
  float* __restrict__ Out = half ? Q : P;
  const float* __restrict__ Wt = W1pT + (half ? Cc * Cc : 0);  // [128 c][128 o]
  int tid = threadIdx.x;
  int r0 = blockIdx.x * 32;
  for (int i = tid; i < 32 * 128; i += 256) {
    int r = i >> 7, c = i & 127;
    Ar[r][c] = A[(r0 + r) * Cc + c];
  }
  __syncthreads();
  int tx = tid & 31, ty = tid >> 5;
  float acc[4][4] = {};
  #pragma unroll 4
  for (int c = 0; c < 128; ++c) {
    float4 w = *(const float4*)&Wt[c * Cc + tx * 4];
    float a0 = Ar[ty * 4 + 0][c], a1 = Ar[ty * 4 + 1][c];
    float a2 = Ar[ty * 4 + 2][c], a3 = Ar[ty * 4 + 3][c];
    acc[0][0] += a0 * w.x; acc[0][1] += a0 * w.y; acc[0][2] += a0 * w.z; acc[0][3] += a0 * w.w;
    acc[1][0] += a1 * w.x; acc[1][1] += a1 * w.y; acc[1][2] += a1 * w.z; acc[1][3] += a1 * w.w;
    acc[2][0] += a2 * w.x; acc[2][1] += a2 * w.y; acc[2][2] += a2 * w.z; acc[2][3] += a2 * w.w;
    acc[3][0] += a3 * w.x; acc[3][1] += a3 * w.y; acc[3][2] += a3 * w.z; acc[3][3] += a3 * w.w;
  }
  #pragma unroll
  for (int i = 0; i < 4; ++i) {
    int node = r0 + ty * 4 + i;
    float4 v = make_float4(acc[i][0], acc[i][1], acc[i][2], acc[i][3]);
    *(float4*)&Out[node * Cc + tx * 4] = v;
  }
}

// BN2 stats + z materialization. 1250 blocks x 512 threads: FOUR half-wave
// stripes (y=0..3) interleave by OCTETS within the same 512-edge sorted-tgt
// window -> P-locality kept, occupancy 2x vs round 14, 8-deep gather ILP kept.
// LDS-combine partials; 1 atomic per channel per block (unchanged count).
__global__ __launch_bounds__(512) void k_stats2(const float* __restrict__ P,
                                                const float* __restrict__ Q,
                                                const float* __restrict__ b1p,
                                                const int* __restrict__ tgt,
                                                const int* __restrict__ src,
                                                float* __restrict__ stats,
                                                unsigned short* __restrict__ zout) {
  __shared__ float s2[3][Cc], q2[3][Cc];
  int c = threadIdx.x & 127;
  int y = threadIdx.x >> 7;       // 0..3
  int e0 = blockIdx.x * 512;
  float b = b1p[c];
  float s = 0.f, q = 0.f;
  for (int e = e0 + y * 8; e < e0 + 512; e += 32) {
    int t[8], sr[8];
    #pragma unroll
    for (int j = 0; j < 8; ++j) { t[j] = tgt[e + j]; sr[j] = src[e + j]; }
    float pv[8], qv[8];
    #pragma unroll
    for (int j = 0; j < 8; ++j) pv[j] = P[(size_t)t[j] * Cc + c];
    #pragma unroll
    for (int j = 0; j < 8; ++j) qv[j] = Q[(size_t)sr[j] * Cc + c];
    float z[8];
    #pragma unroll
    for (int j = 0; j < 8; ++j) {
      z[j] = fmaxf(pv[j] + qv[j] + b, 0.f);
      zout[(size_t)(e + j) * 256 + c] = f2bf(z[j]);
    }
    s += ((z[0] + z[1]) + (z[2] + z[3])) + ((z[4] + z[5]) + (z[6] + z[7]));
    q += ((z[0]*z[0] + z[1]*z[1]) + (z[2]*z[2] + z[3]*z[3]))
       + ((z[4]*z[4] + z[5]*z[5]) + (z[6]*z[6] + z[7]*z[7]));
  }
  if (y) { s2[y - 1][c] = s; q2[y - 1][c] = q; }
  __syncthreads();
  if (!y) {
    atomicAdd(&stats[512 + c], ((s + s2[0][c]) + (s2[1][c] + s2[2][c])));
    atomicAdd(&stats[640 + c], ((q + q2[0][c]) + (q2[1][c] + q2[2][c])));
  }
}

// fold BN2 into W2, emit bf16 [o][c] weights + fp32 bias
__global__ void k_fold2(const float* __restrict__ W2, const float* __restrict__ b2,
                        const float* __restrict__ g2, const float* __restrict__ be2,
                        const float* __restrict__ stats,
                        unsigned short* __restrict__ W2bf, float* __restrict__ b2p) {
  __shared__ float red[Cc];
  int o = blockIdx.x, c = threadIdx.x;
  const float inv = 1.0f / (float)NE;
  float mu = stats[512 + c] * inv;
  float var = stats[640 + c] * inv - mu * mu;
  float a = g2[c] * rsqrtf(var + BN_EPS);
  float cc = be2[c] - mu * a;
  float w = W2[o * Cc + c];
  W2bf[o * Cc + c] = f2bf(w * a);
  red[c] = w * cc;
  __syncthreads();
  for (int s = 64; s > 0; s >>= 1) { if (c < s) red[c] += red[c + s]; __syncthreads(); }
  if (c == 0) b2p[o] = b2[o] + red[0];
}

// out[e][o] = relu( z[e]@W2' + b2' ): pure streaming bf16 MFMA GEMM.
// Operand-SWAPPED (A=W rows=outs, B=z cols=edges; correctness HW-verified
// round 9): each lane stores 4 contiguous outs per tile -> 8 float4 stores
// instead of 32 scalar. z read from out-row slot into regs before stores.
#define WPAD 136
__global__ __launch_bounds__(256) void k_out_mfma(const unsigned short* __restrict__ zin,
                                                  const unsigned short* __restrict__ W2bf,
                                                  const float* __restrict__ b2p,
                                                  float* __restrict__ out) {
  __shared__ unsigned short Wl[128 * WPAD];  // 34816 B -> 4 blocks/CU
  int tid = threadIdx.x;
  int e0 = blockIdx.x * 64;

  // stage folded-bf16 W2 [o][c] -> LDS (coalesced 16B loads)
  for (int i = tid; i < 2048; i += 256) {
    int row = i >> 4, col = (i & 15) * 8;
    *(bf16x8*)&Wl[row * WPAD + col] = *(const bf16x8*)&W2bf[row * Cc + col];
  }

  int w = tid >> 6, l = tid & 63;
  int la = l & 15, kb = l >> 4;
  int e = e0 + w * 16 + la;

  // load all 4 B-fragments (full z row slice) into registers up front
  bf16x8 zfr[4];
  #pragma unroll
  for (int kk = 0; kk < 4; ++kk)
    zfr[kk] = *(const bf16x8*)&zin[(size_t)e * 256 + kk * 32 + kb * 8];
  __syncthreads();

  f32x4 acc[8];
  #pragma unroll
  for (int n = 0; n < 8; ++n) acc[n] = (f32x4){0.f, 0.f, 0.f, 0.f};

  #pragma unroll
  for (int kk = 0; kk < 4; ++kk) {        // K = 128 in 4 steps of 32
    #pragma unroll
    for (int n = 0; n < 8; ++n) {         // 8 out-tiles of 16
      bf16x8 wa = *(const bf16x8*)&Wl[(n * 16 + la) * WPAD + kk * 32 + kb * 8];
      acc[n] = __builtin_amdgcn_mfma_f32_16x16x32_bf16(wa, zfr[kk], acc[n], 0, 0, 0);
    }
  }

  // D layout: col(edge) = la, row(out) = kb*4 + r -> contiguous float4 per lane
  #pragma unroll
  for (int n = 0; n < 8; ++n) {
    int o0 = n * 16 + kb * 4;
    float4 bb = *(const float4*)&b2p[o0];
    float4 v;
    v.x = fmaxf(acc[n][0] + bb.x, 0.f);
    v.y = fmaxf(acc[n][1] + bb.y, 0.f);
    v.z = fmaxf(acc[n][2] + bb.z, 0.f);
    v.w = fmaxf(acc[n][3] + bb.w, 0.f);
    *(float4*)&out[(size_t)e * Cc + o0] = v;
  }
}

extern "C" void kernel_launch(void* const* d_in, const int* in_sizes, int n_in,
                              void* d_out, int out_size, void* d_ws, size_t ws_size,
                              hipStream_t stream) {
  (void)in_sizes; (void)n_in; (void)out_size; (void)ws_size;
  const float* x   = (const float*)d_in[0];
  const float* g1  = (const float*)d_in[1];
  const float* be1 = (const float*)d_in[2];
  const float* W1  = (const float*)d_in[3];
  const float* b1  = (const float*)d_in[4];
  const float* g2  = (const float*)d_in[5];
  const float* be2 = (const float*)d_in[6];
  const float* W2  = (const float*)d_in[7];
  const float* b2  = (const float*)d_in[8];
  const int* tgt   = (const int*)d_in[9];
  const int* src   = (const int*)d_in[10];

  float* ws  = (float*)d_ws;
  float* out = (float*)d_out;

  float* P     = ws + WS_P;
  float* Q     = ws + WS_Q;
  float* cntT  = ws + WS_CNTT;
  int*   cntS  = (int*)(ws + WS_CNTS);
  float* stats = ws + WS_STATS;
  float* W1pT  = ws + WS_W1PT;
  float* b1p   = ws + WS_B1P;
  unsigned short* W2bf = (unsigned short*)(ws + WS_W2BF);
  float* b2p   = ws + WS_B2P;
  float* nbr   = out;  // scratch: overwritten by k_stats2's z + k_out_mfma

  k_zero  <<<dim3((NN + 255) / 256), dim3(256), 0, stream>>>(stats, cntS);
  k_cnt   <<<dim3(NE / 256),        dim3(256), 0, stream>>>(src, cntS);
  k_nbr   <<<dim3(NN),              dim3(Cc),  0, stream>>>(x, tgt, src, nbr, cntT);
  k_stats1<<<dim3(256),             dim3(Cc),  0, stream>>>(nbr, x, cntT, cntS, stats);
  k_fold1 <<<dim3(Cc),              dim3(C2),  0, stream>>>(W1, b1, g1, be1, stats, W1pT, b1p);
  k_pq    <<<dim3(NN / 32, 2),      dim3(256), 0, stream>>>(nbr, x, W1pT, P, Q);
  k_stats2<<<dim3(NE / 512),        dim3(512), 0, stream>>>(P, Q, b1p, tgt, src, stats,
                                                            (unsigned short*)out);
  k_fold2 <<<dim3(Cc),              dim3(Cc),  0, stream>>>(W2, b2, g2, be2, stats, W2bf, b2p);
  k_out_mfma<<<dim3(NE / 64),       dim3(256), 0, stream>>>((const unsigned short*)out,
                                                            W2bf, b2p, out);
}